// Round 9
// baseline (262.035 us; speedup 1.0000x reference)
//
#include <hip/hip_runtime.h>

#define NSEQ  1536
#define HEADS 8
#define NREL  3071   // 2N-1
#define NRELP 3072   // padded (row 3071 never read through the shift mux)

typedef __bf16 bf16;
typedef __bf16 bf16x8 __attribute__((ext_vector_type(8)));
typedef __bf16 bf16x4 __attribute__((ext_vector_type(4)));
typedef float  f32x4  __attribute__((ext_vector_type(4)));

static __device__ __forceinline__ f32x4 mfma16(bf16x8 a, bf16x8 b, f32x4 c) {
  return __builtin_amdgcn_mfma_f32_16x16x32_bf16(a, b, c, 0, 0, 0);
}

// async global->LDS, 16B per lane; lds base wave-uniform (HW adds lane*16)
static __device__ __forceinline__ void gload_lds16(const bf16* g, bf16* l) {
  __builtin_amdgcn_global_load_lds((const __attribute__((address_space(1))) void*)g,
                                   (__attribute__((address_space(3))) void*)l, 16, 0, 0);
}

// DPP-based 16-lane (row) sum
#define DPP_F(v, ctrl) __int_as_float(__builtin_amdgcn_update_dpp(0, __float_as_int(v), ctrl, 0xF, 0xF, true))
static __device__ __forceinline__ float rowsum16(float v) {
  v += DPP_F(v, 0xB1);
  v += DPP_F(v, 0x4E);
  v += DPP_F(v, 0x124);
  v += DPP_F(v, 0x128);
  return v;
}

// ---------- one-launch prep: cast x, cast pos, transpose Wq/Wk/Wv/Wout/Wrel ----------
__global__ __launch_bounds__(256) void prep(const float* __restrict__ x, const float* __restrict__ pos,
                                            const float* __restrict__ Wq, const float* __restrict__ Wk,
                                            const float* __restrict__ Wv, const float* __restrict__ Wout,
                                            const float* __restrict__ Wrel,
                                            bf16* __restrict__ xb, bf16* __restrict__ posb,
                                            bf16* __restrict__ WT, bf16* __restrict__ WoT,
                                            bf16* __restrict__ WrT) {
  int blk = blockIdx.x;
  if (blk < 4608) {  // cast x: 3072*1536 elems, x4 vectorized
    int i = blk * 256 + threadIdx.x;
    float4 v = ((const float4*)x)[i];
    bf16x4 o;
    o[0] = (bf16)v.x; o[1] = (bf16)v.y; o[2] = (bf16)v.z; o[3] = (bf16)v.w;
    ((bf16x4*)xb)[i] = o;
    return;
  }
  blk -= 4608;
  if (blk < 576) {  // cast pos: 3071*192 elems
    int i = blk * 256 + threadIdx.x;
    if (i < (NREL * 192 / 4)) {
      float4 v = ((const float4*)pos)[i];
      bf16x4 o;
      o[0] = (bf16)v.x; o[1] = (bf16)v.y; o[2] = (bf16)v.z; o[3] = (bf16)v.w;
      ((bf16x4*)posb)[i] = o;
    }
    return;
  }
  blk -= 576;
  const float* in; bf16* out; int C, ostride, orowoff, cx, ry;
  if (blk < 768)       { in = Wq;   out = WT;  C = 512;  ostride = 1536; orowoff = 0;    cx = blk % 16; ry = blk / 16; }
  else if (blk < 1536) { blk -= 768;  in = Wk;   out = WT;  C = 512;  ostride = 1536; orowoff = 512;  cx = blk % 16; ry = blk / 16; }
  else if (blk < 2304) { blk -= 1536; in = Wv;   out = WT;  C = 512;  ostride = 1536; orowoff = 1024; cx = blk % 16; ry = blk / 16; }
  else if (blk < 3072) { blk -= 2304; in = Wout; out = WoT; C = 1536; ostride = 512;  orowoff = 0;    cx = blk % 48; ry = blk / 48; }
  else                 { blk -= 3072; in = Wrel; out = WrT; C = 512;  ostride = 192;  orowoff = 0;    cx = blk % 16; ry = blk / 16; }
  __shared__ float t[32][33];
  int tx = threadIdx.x & 31, ty = threadIdx.x >> 5;  // 32 x 8
  int r0 = ry * 32, c0 = cx * 32;
#pragma unroll
  for (int i = 0; i < 4; i++)
    t[ty + 8 * i][tx] = in[(size_t)(r0 + ty + 8 * i) * C + c0 + tx];
  __syncthreads();
#pragma unroll
  for (int i = 0; i < 4; i++)
    out[(size_t)(c0 + ty + 8 * i + orowoff) * ostride + r0 + tx] = (bf16)t[tx][ty + 8 * i];
}

// ---------- 8-wave GEMM core: 128(M)x64(N) tile, BK=64, XOR-swizzled LDS (R7-best) ----------
static __device__ __forceinline__ void gemm_core64(const bf16* __restrict__ A, const bf16* __restrict__ BT,
                                                   int Klen, int ldk, int m0, int n0, int M,
                                                   bf16* sa, bf16* sb, f32x4 acc[2][2]) {
  int tid = threadIdx.x, wave = tid >> 6, lane = tid & 63;
  int l15 = lane & 15, quad = lane >> 4;
  int lrow = lane >> 3, lcg = lane & 7;
  int wr = wave & 3, wc = wave >> 2;
  int swz = (lcg ^ lrow) * 8;  // row&7 == lrow for all staged rows

  // wave stages 16 A-rows (2 DMAs) and 8 B-rows (1 DMA)
  int rowA = wave * 16 + lrow;
  int ra0 = m0 + rowA;     if (ra0 > M - 1) ra0 = M - 1;
  int ra1 = m0 + rowA + 8; if (ra1 > M - 1) ra1 = M - 1;
  const bf16* pA0 = A + (size_t)ra0 * ldk + swz;
  const bf16* pA1 = A + (size_t)ra1 * ldk + swz;
  const bf16* pB = BT + (size_t)(n0 + wave * 8 + lrow) * ldk + swz;
  bf16* dA = sa + (wave * 16) * 64;
  bf16* dB = sb + (wave * 8) * 64;

  int swzA = (quad ^ (l15 & 7)) * 8;
  int swzB = ((4 + quad) ^ (l15 & 7)) * 8;
  const bf16* ar = sa + (wr * 32 + l15) * 64;
  const bf16* br = sb + (wc * 32 + l15) * 64;

  for (int k0 = 0; k0 < Klen; k0 += 64) {
    __syncthreads();
    gload_lds16(pA0 + k0, dA);
    gload_lds16(pA1 + k0, dA + 512);
    gload_lds16(pB + k0, dB);
    __syncthreads();
#pragma unroll
    for (int kq = 0; kq < 2; kq++) {
      int sz = kq ? swzB : swzA;
      bf16x8 af[2], bfr[2];
      af[0] = *(const bf16x8*)&ar[sz];
      af[1] = *(const bf16x8*)&ar[16 * 64 + sz];
      bfr[0] = *(const bf16x8*)&br[sz];
      bfr[1] = *(const bf16x8*)&br[16 * 64 + sz];
#pragma unroll
      for (int ct = 0; ct < 2; ct++)
#pragma unroll
        for (int rt = 0; rt < 2; rt++)
          acc[rt][ct] = mfma16(af[rt], bfr[ct], acc[rt][ct]);
    }
  }
}

// ---------- fused qkv + rel projection (128x64 tiles, 512 threads, R7-best) ----------
// grid (24, 32); y 0-7 -> q cols (h = y), 8-15 -> k (h = y-8), 16-23 -> v (h = y-16,
// transposed to vt), 24-31 -> rel projection with repack epilogue.
__global__ __launch_bounds__(512, 4) void gemm_qkvrel(const bf16* __restrict__ xb, const bf16* __restrict__ WT,
                                                      const bf16* __restrict__ posb, const bf16* __restrict__ WrT,
                                                      const float* __restrict__ cb, const float* __restrict__ pb,
                                                      bf16* __restrict__ qc, bf16* __restrict__ qp,
                                                      bf16* __restrict__ kb, bf16* __restrict__ vt,
                                                      bf16* __restrict__ rk) {
  __shared__ __align__(16) bf16 smem[128 * 64 + 64 * 64];  // sa | sb ; tv (128*66) overlays
  bf16* sa = smem;
  bf16* sb = smem + 128 * 64;
  bf16* tv = smem;
  int tid = threadIdx.x, wave = tid >> 6, lane = tid & 63;
  int l15 = lane & 15, quad = lane >> 4;
  int wr = wave & 3, wc = wave >> 2;
  int m0 = blockIdx.x * 128;
  int y = blockIdx.y;
  f32x4 acc[2][2] = {};
  if (y >= 24) {
    // ---- rel projection path ----
    int n0 = (y - 24) * 64;
    gemm_core64(posb, WrT, 192, 192, m0, n0, NREL, sa, sb, acc);
#pragma unroll
    for (int rt = 0; rt < 2; rt++)
#pragma unroll
      for (int ct = 0; ct < 2; ct++)
#pragma unroll
        for (int r = 0; r < 4; r++) {
          int row = m0 + wr * 32 + rt * 16 + quad * 4 + r;
          if (row < NREL) {
            int col = n0 + wc * 32 + ct * 16 + l15;
            rk[((size_t)(col >> 6) * NRELP + row) * 64 + (col & 63)] = (bf16)acc[rt][ct][r];
          }
        }
    return;
  }
  gemm_core64(xb, WT, 1536, 1536, m0, y * 64, 3072, sa, sb, acc);
  int b = m0 / NSEQ, nseq0 = m0 % NSEQ;
  if (y < 16) {
    bool isq = y < 8;
    int h = y & 7;
#pragma unroll
    for (int rt = 0; rt < 2; rt++)
#pragma unroll
      for (int ct = 0; ct < 2; ct++)
#pragma unroll
        for (int r = 0; r < 4; r++) {
          int row = nseq0 + wr * 32 + rt * 16 + quad * 4 + r;
          int d = wc * 32 + ct * 16 + l15;       // within-head col
          int col = h * 64 + d;                  // within q|k 512-range (bias index)
          size_t o = ((size_t)(b * 8 + h) * NSEQ + row) * 64 + d;
          float v = acc[rt][ct][r];
          if (isq) {
            // 0.125 * log2(e): scores land directly in exp2 domain
            float qv = v * 0.18033688011f;
            qc[o] = (bf16)(qv + cb[col] * 1.44269504089f);
            qp[o] = (bf16)(qv + pb[col] * 1.44269504089f);
          } else {
            kb[o] = (bf16)v;
          }
        }
  } else {
    // v: transpose 128(n) x 64(dv) tile through LDS -> vt [bh][dv][n]; single head h = y-16
    int h = y - 16;
    __syncthreads();  // core's last reads done before tv overlay
#pragma unroll
    for (int rt = 0; rt < 2; rt++)
#pragma unroll
      for (int ct = 0; ct < 2; ct++)
#pragma unroll
        for (int r = 0; r < 4; r++)
          tv[(wr * 32 + rt * 16 + quad * 4 + r) * 66 + wc * 32 + ct * 16 + l15] = (bf16)acc[rt][ct][r];
    __syncthreads();
    int n = tid & 127, dq = tid >> 7;  // 128 x 4
#pragma unroll
    for (int i = 0; i < 16; i++) {
      int dv = i * 4 + dq;
      vt[((size_t)(b * 8 + h) * 64 + dv) * NSEQ + nseq0 + n] = tv[n * 66 + dv];
    }
  }
}

// ---------- output projection GEMM (+bias), fp32 out (128x64 tiles, 512 threads, R7-best) ----------
__global__ __launch_bounds__(512, 4) void gemm_out(const bf16* __restrict__ A, const bf16* __restrict__ BT,
                                                   float* __restrict__ C, const float* __restrict__ bias) {
  __shared__ __align__(16) bf16 sa[128 * 64];
  __shared__ __align__(16) bf16 sb[64 * 64];
  int tid = threadIdx.x, wave = tid >> 6, lane = tid & 63;
  int l15 = lane & 15, quad = lane >> 4;
  int wr = wave & 3, wc = wave >> 2;
  int m0 = blockIdx.x * 128, n0 = blockIdx.y * 64;
  f32x4 acc[2][2] = {};
  gemm_core64(A, BT, 512, 512, m0, n0, 3072, sa, sb, acc);
#pragma unroll
  for (int rt = 0; rt < 2; rt++)
#pragma unroll
    for (int ct = 0; ct < 2; ct++)
#pragma unroll
      for (int r = 0; r < 4; r++) {
        int row = m0 + wr * 32 + rt * 16 + quad * 4 + r;
        int col = n0 + wc * 32 + ct * 16 + l15;
        C[(size_t)row * 1536 + col] = acc[rt][ct][r] + bias[col];
      }
}

// ---------- fused flash attention v12: LDS-lean (32 KB) + V double-buffered in registers ----------
// grid (24 q-blocks of 64 rows, 16 bh, 2 kz); block 256 = 4 waves; wave w owns rows i0+16w..+16.
// LDS: K (8 KB, staged) + srel ring (16 KB) + pls (8 KB). V's B-fragments are loaded per-lane
// from vt ONE TILE AHEAD into register buffers vfA/vfB (swapped via 2x loop unroll, all static
// indices) -- same prefetch distance as the R2 LDS path, ~40% less DS-pipe traffic (R8's
// regression isolated to its zero prefetch distance, not the traffic cut; FETCH was unchanged).
// Softmax: fixed shift 8, exp2 domain (q pre-scaled by log2e in the projection epilogue).
__global__ __launch_bounds__(256, 4) void attn(const bf16* __restrict__ qc, const bf16* __restrict__ qp,
                                               const bf16* __restrict__ kb, const bf16* __restrict__ vt,
                                               const bf16* __restrict__ rk,
                                               float* __restrict__ Opart, float* __restrict__ mlp) {
  __shared__ __align__(16) bf16 sk[64 * 64];     // rows = key, 8 slots of 16B, slot^=(row&7)
  __shared__ __align__(16) bf16 srel[128 * 64];  // 2-slot ring of 64-row rel windows
  __shared__ __align__(16) bf16 pls[4][16 * 64]; // per-wave P transpose buffer, col ^= (row>>1)<<3
  int qb = blockIdx.x, bh = blockIdx.y, kz = blockIdx.z;
  int h = bh & 7;
  int i0 = qb * 64;
  int wave = threadIdx.x >> 6, lane = threadIdx.x & 63;
  int l15 = lane & 15, quad = lane >> 4;
  int lrow = lane >> 3, lcg = lane & 7;
  const bf16* qcb = qc + (size_t)bh * NSEQ * 64;
  const bf16* qpb = qp + (size_t)bh * NSEQ * 64;
  const bf16* kbb = kb + (size_t)bh * NSEQ * 64;
  const bf16* vtb = vt + (size_t)bh * 64 * NSEQ;
  const bf16* rkh = rk + (size_t)h * NRELP * 64;
  bf16* plsw = pls[wave];

  int qrow = i0 + wave * 16 + l15;
  bf16x8 aqc0 = *(const bf16x8*)(qcb + (size_t)qrow * 64 + quad * 8);
  bf16x8 aqc1 = *(const bf16x8*)(qcb + (size_t)qrow * 64 + 32 + quad * 8);
  bf16x8 aqp0 = *(const bf16x8*)(qpb + (size_t)qrow * 64 + quad * 8);
  bf16x8 aqp1 = *(const bf16x8*)(qpb + (size_t)qrow * 64 + 32 + quad * 8);

  // band-shift cross-lane setup: rl = quad*4+r
  int bidx[4];
  bool hisel[4];
#pragma unroll
  for (int r = 0; r < 4; r++) {
    int rl = quad * 4 + r;
    bidx[r] = (quad * 16 + ((l15 + 15 - rl) & 15)) << 2;
    hisel[r] = l15 > rl;
  }

  // ---- staging pointers: pre-swizzled global source, linear LDS dest ----
  int swz = (lcg ^ lrow) * 8;
  int jb = 23 + kz * 12 - qb;  // Rbase>>6 at jt=0; window jt reads 64-row windows jb+jt, jb+jt+1
  const bf16* pK = kbb + (size_t)(kz * 768 + wave * 16 + lrow) * 64 + swz;
  const bf16* pR = rkh + (size_t)(jb + 1) * 4096 + (size_t)(wave * 16 + lrow) * 64 + swz;
  bf16* wK = sk + (wave * 16 + lrow) * 64 + lcg * 8;   // linear col; source carries the XOR
  int wRoff = (wave * 16 + lrow) * 64 + lcg * 8;       // + ring-slot row offset at write time
  // per-lane V-fragment pointer (next tile to load): vt[dv = c*16+l15][.. + ks*32 + quad*8]
  const bf16* pVf = vtb + (size_t)l15 * NSEQ + kz * 768 + quad * 8;

  // prologue: low rel window [64*jb, 64*jb+64) into slot (jb&1) via DMA (drains at first barrier)
  {
    const bf16* pP = rkh + (size_t)jb * 4096 + (size_t)(wave * 16 + lrow) * 64 + swz;
    bf16* dP = srel + ((jb & 1) * 64 + wave * 16) * 64;
#pragma unroll
    for (int t = 0; t < 2; t++)
      gload_lds16(pP + t * 512, dP + t * 512);
  }
  // prologue: tile-0 K + high-window rel into staging regs; tile-0 V frags into vfA
  float4 kr0 = *(const float4*)(pK), kr1 = *(const float4*)(pK + 512);             pK += 4096;
  float4 rr0 = *(const float4*)(pR), rr1 = *(const float4*)(pR + 512);             pR += 4096;
  bf16x8 vfA[8], vfB[8];
#pragma unroll
  for (int c = 0; c < 4; c++)
#pragma unroll
    for (int ks = 0; ks < 2; ks++)
      vfA[c * 2 + ks] = *(const bf16x8*)(pVf + (size_t)c * 16 * NSEQ + ks * 32);
  pVf += 64;
  int pxor = (jb & 1) << 6;  // logical loc -> physical row: phys = loc ^ pxor

  // read-side hoists (all row&7 terms reduce to l15&7)
  int swzA = (quad ^ (l15 & 7)) * 8;
  int swzB = ((4 + quad) ^ (l15 & 7)) * 8;
  int rb0 = (3 - wave) * 16 + l15;       // locbase + l15
  int pxl = (l15 >> 1) << 3;             // pls read xor
  const bf16* plr = plsw + l15 * 64;

  f32x4 acco[4] = {};
  float li[4] = {0.0f, 0.0f, 0.0f, 0.0f};

  // one attention tile; consumes VFC (this tile's V frags), prefetches VFN (next tile's)
#define ATTN_TILE(JT, VFC, VFN)                                                           \
  {                                                                                       \
    __syncthreads();  /* prior tile's LDS reads done; drains vmcnt for staged regs */     \
    *(float4*)(wK) = kr0;        *(float4*)(wK + 512) = kr1;                              \
    {                                                                                     \
      bf16* wR = srel + (pxor ^ 64) * 64 + wRoff;  /* the slot NOT read last tile */      \
      *(float4*)(wR) = rr0;      *(float4*)(wR + 512) = rr1;                              \
    }                                                                                     \
    __syncthreads();  /* writes visible (no vmcnt ops in flight here) */                  \
    if ((JT) < 11) {  /* issue tile-(JT+1) loads; they fly under this tile's compute */   \
      kr0 = *(const float4*)(pK); kr1 = *(const float4*)(pK + 512);        pK += 4096;    \
      rr0 = *(const float4*)(pR); rr1 = *(const float4*)(pR + 512);        pR += 4096;    \
      _Pragma("unroll")                                                                   \
      for (int c = 0; c < 4; c++)                                                         \
        _Pragma("unroll")                                                                 \
        for (int ks = 0; ks < 2; ks++)                                                    \
          VFN[c * 2 + ks] = *(const bf16x8*)(pVf + (size_t)c * 16 * NSEQ + ks * 32);      \
      pVf += 64;                                                                          \
    }                                                                                     \
    /* ---- content scores ---- */                                                        \
    f32x4 s[4] = {};                                                                      \
    _Pragma("unroll")                                                                     \
    for (int c = 0; c < 4; c++) {                                                         \
      const bf16* kp = sk + (c * 16 + l15) * 64;                                          \
      s[c] = mfma16(aqc0, *(const bf16x8*)(kp + swzA), s[c]);                             \
      s[c] = mfma16(aqc1, *(const bf16x8*)(kp + swzB), s[c]);                             \
    }                                                                                     \
    /* ---- banded rel scores (5 tiles of 16 from the ring window) ---- */                \
    f32x4 sb5[5];                                                                         \
    _Pragma("unroll")                                                                     \
    for (int cc = 0; cc < 5; cc++) {                                                      \
      const bf16* rp = srel + ((rb0 + cc * 16) ^ pxor) * 64;                              \
      f32x4 z = {};                                                                       \
      z = mfma16(aqp0, *(const bf16x8*)(rp + swzA), z);                                   \
      sb5[cc] = mfma16(aqp1, *(const bf16x8*)(rp + swzB), z);                             \
    }                                                                                     \
    /* ---- shift-gather via bpermute ---- */                                             \
    _Pragma("unroll")                                                                     \
    for (int r = 0; r < 4; r++) {                                                         \
      float bp[5];                                                                        \
      _Pragma("unroll")                                                                   \
      for (int cc = 0; cc < 5; cc++)                                                      \
        bp[cc] = __int_as_float(__builtin_amdgcn_ds_bpermute(bidx[r], __float_as_int(sb5[cc][r]))); \
      _Pragma("unroll")                                                                   \
      for (int c = 0; c < 4; c++)                                                         \
        s[c][r] += hisel[r] ? bp[c + 1] : bp[c];                                          \
    }                                                                                     \
    /* ---- fixed-shift exp2 + accumulate (8*log2e = 11.5415603) ---- */                  \
    _Pragma("unroll")                                                                     \
    for (int c = 0; c < 4; c++)                                                           \
      _Pragma("unroll")                                                                   \
      for (int r = 0; r < 4; r++) {                                                       \
        float p = __builtin_amdgcn_exp2f(s[c][r] - 11.5415603f);                          \
        bf16 pbh = (bf16)p;                                                               \
        li[r] += (float)pbh;  /* consistent with what PV consumes */                      \
        int prow = quad * 4 + r;                                                          \
        plsw[prow * 64 + ((c * 16 + l15) ^ ((prow >> 1) << 3))] = pbh;                    \
      }                                                                                   \
    /* ---- PV: A = P via pls, B = V fragments (prefetched last tile) ---- */             \
    _Pragma("unroll")                                                                     \
    for (int ks = 0; ks < 2; ks++) {                                                      \
      bf16x8 ap = *(const bf16x8*)(plr + ((ks * 32 + quad * 8) ^ pxl));                   \
      _Pragma("unroll")                                                                   \
      for (int c = 0; c < 4; c++)                                                         \
        acco[c] = mfma16(ap, VFC[c * 2 + ks], acco[c]);                                   \
    }                                                                                     \
    pxor ^= 64;                                                                           \
  }

  for (int jt2 = 0; jt2 < 12; jt2 += 2) {
    ATTN_TILE(jt2, vfA, vfB);
    ATTN_TILE(jt2 + 1, vfB, vfA);
  }
#undef ATTN_TILE

  // ---- final row sums + write unnormalized partials ----
#pragma unroll
  for (int r = 0; r < 4; r++)
    li[r] = rowsum16(li[r]);
  int qt16 = qb * 4 + wave;
  size_t pbase = ((size_t)(bh * 96 + qt16) * 2 + kz);
#pragma unroll
  for (int c = 0; c < 4; c++)
#pragma unroll
    for (int r = 0; r < 4; r++)
      Opart[pbase * 1024 + (quad * 4 + r) * 64 + c * 16 + l15] = acco[c][r];
  if (l15 == 0) {
#pragma unroll
    for (int r = 0; r < 4; r++)
      mlp[pbase * 16 + quad * 4 + r] = li[r];
  }
}

// ---------- merge the 2 key-split partials -> O bf16 [b][n][h][dv] ----------
__global__ void attn_merge(const float* __restrict__ Opart, const float* __restrict__ mlp,
                           bf16* __restrict__ O) {
  int qt = blockIdx.x, bh = blockIdx.y;
  int b = bh >> 3, h = bh & 7;
  int col = threadIdx.x & 63, rg = threadIdx.x >> 6;
  size_t base = (size_t)(bh * 96 + qt) * 2;
#pragma unroll
  for (int rr = 0; rr < 4; rr++) {
    int row = rg * 4 + rr;
    float L = mlp[base * 16 + row] + mlp[(base + 1) * 16 + row];
    float v = Opart[base * 1024 + row * 64 + col] + Opart[(base + 1) * 1024 + row * 64 + col];
    O[((size_t)(b * NSEQ + qt * 16 + row) * 8 + h) * 64 + col] = (bf16)(v / L);
  }
}

extern "C" void kernel_launch(void* const* d_in, const int* in_sizes, int n_in,
                              void* d_out, int out_size, void* d_ws, size_t ws_size,
                              hipStream_t stream) {
  const float* x    = (const float*)d_in[0];
  const float* Wq   = (const float*)d_in[1];
  const float* Wk   = (const float*)d_in[2];
  const float* Wv   = (const float*)d_in[3];
  const float* Wrel = (const float*)d_in[4];
  const float* Wout = (const float*)d_in[5];
  const float* bout = (const float*)d_in[6];
  const float* cb   = (const float*)d_in[7];
  const float* pb   = (const float*)d_in[8];
  const float* pos  = (const float*)d_in[9];
  float* out = (float*)d_out;

  char* ws = (char*)d_ws;
  size_t off = 0;
  auto alloc = [&](size_t bytes) {
    char* p = ws + off;
    off = (off + bytes + 255) & ~(size_t)255;
    return p;
  };
  bf16*  xb    = (bf16*)alloc(3072UL * 1536 * 2);
  bf16*  WT    = (bf16*)alloc(1536UL * 1536 * 2);   // [oc(q|k|v)][k]
  bf16*  WoT   = (bf16*)alloc(1536UL * 512 * 2);    // [outdim][k]
  bf16*  WrT   = (bf16*)alloc(512UL * 192 * 2);     // [oc][k]
  bf16*  posb  = (bf16*)alloc((size_t)NREL * 192 * 2);
  bf16*  qcb   = (bf16*)alloc(16UL * NSEQ * 64 * 2);
  bf16*  qpb   = (bf16*)alloc(16UL * NSEQ * 64 * 2);
  bf16*  kbb   = (bf16*)alloc(16UL * NSEQ * 64 * 2);
  bf16*  vtb   = (bf16*)alloc(16UL * NSEQ * 64 * 2);
  bf16*  rkb   = (bf16*)alloc(8UL * NRELP * 64 * 2);
  bf16*  Ob    = (bf16*)alloc(3072UL * 512 * 2);
  float* Opart = (float*)alloc(16UL * 96 * 2 * 1024 * 4);
  float* mlpw  = (float*)alloc(16UL * 96 * 2 * 16 * 4);

  // 1. all casts + weight transposes in one launch
  prep<<<dim3(8352), 256, 0, stream>>>(x, pos, Wq, Wk, Wv, Wout, Wrel, xb, posb, WT, WoT, WrT);
  // 2. qkv + rel projection, 128x64 8-wave tiles (R7-best)
  gemm_qkvrel<<<dim3(24, 32), 512, 0, stream>>>(xb, WT, posb, WrT, cb, pb, qcb, qpb, kbb, vtb, rkb);
  // 3. fused flash attention (LDS-lean, V double-buffered in registers)
  attn<<<dim3(24, 16, 2), 256, 0, stream>>>(qcb, qpb, kbb, vtb, rkb, Opart, mlpw);
  // 4. merge key-split partials
  attn_merge<<<dim3(96, 16), 256, 0, stream>>>(Opart, mlpw, Ob);
  // 5. output projection + bias, 128x64 8-wave tiles (R7-best)
  gemm_out<<<dim3(24, 24), 512, 0, stream>>>(Ob, WoT, out, bout);
}

// Round 10
// 167.536 us; speedup vs baseline: 1.5641x; 1.5641x over previous
//
#include <hip/hip_runtime.h>

#define NSEQ  1536
#define HEADS 8
#define NREL  3071   // 2N-1
#define NRELP 3072   // padded (row 3071 never read through the shift mux)

typedef __bf16 bf16;
typedef __bf16 bf16x8 __attribute__((ext_vector_type(8)));
typedef __bf16 bf16x4 __attribute__((ext_vector_type(4)));
typedef float  f32x4  __attribute__((ext_vector_type(4)));

static __device__ __forceinline__ f32x4 mfma16(bf16x8 a, bf16x8 b, f32x4 c) {
  return __builtin_amdgcn_mfma_f32_16x16x32_bf16(a, b, c, 0, 0, 0);
}

// async global->LDS, 16B per lane; lds base wave-uniform (HW adds lane*16)
static __device__ __forceinline__ void gload_lds16(const bf16* g, bf16* l) {
  __builtin_amdgcn_global_load_lds((const __attribute__((address_space(1))) void*)g,
                                   (__attribute__((address_space(3))) void*)l, 16, 0, 0);
}

// DPP-based 16-lane (row) sum
#define DPP_F(v, ctrl) __int_as_float(__builtin_amdgcn_update_dpp(0, __float_as_int(v), ctrl, 0xF, 0xF, true))
static __device__ __forceinline__ float rowsum16(float v) {
  v += DPP_F(v, 0xB1);
  v += DPP_F(v, 0x4E);
  v += DPP_F(v, 0x124);
  v += DPP_F(v, 0x128);
  return v;
}

// ---------- one-launch prep: cast x, cast pos, transpose Wq/Wk/Wv/Wout/Wrel ----------
__global__ __launch_bounds__(256) void prep(const float* __restrict__ x, const float* __restrict__ pos,
                                            const float* __restrict__ Wq, const float* __restrict__ Wk,
                                            const float* __restrict__ Wv, const float* __restrict__ Wout,
                                            const float* __restrict__ Wrel,
                                            bf16* __restrict__ xb, bf16* __restrict__ posb,
                                            bf16* __restrict__ WT, bf16* __restrict__ WoT,
                                            bf16* __restrict__ WrT) {
  int blk = blockIdx.x;
  if (blk < 4608) {  // cast x: 3072*1536 elems, x4 vectorized
    int i = blk * 256 + threadIdx.x;
    float4 v = ((const float4*)x)[i];
    bf16x4 o;
    o[0] = (bf16)v.x; o[1] = (bf16)v.y; o[2] = (bf16)v.z; o[3] = (bf16)v.w;
    ((bf16x4*)xb)[i] = o;
    return;
  }
  blk -= 4608;
  if (blk < 576) {  // cast pos: 3071*192 elems
    int i = blk * 256 + threadIdx.x;
    if (i < (NREL * 192 / 4)) {
      float4 v = ((const float4*)pos)[i];
      bf16x4 o;
      o[0] = (bf16)v.x; o[1] = (bf16)v.y; o[2] = (bf16)v.z; o[3] = (bf16)v.w;
      ((bf16x4*)posb)[i] = o;
    }
    return;
  }
  blk -= 576;
  const float* in; bf16* out; int C, ostride, orowoff, cx, ry;
  if (blk < 768)       { in = Wq;   out = WT;  C = 512;  ostride = 1536; orowoff = 0;    cx = blk % 16; ry = blk / 16; }
  else if (blk < 1536) { blk -= 768;  in = Wk;   out = WT;  C = 512;  ostride = 1536; orowoff = 512;  cx = blk % 16; ry = blk / 16; }
  else if (blk < 2304) { blk -= 1536; in = Wv;   out = WT;  C = 512;  ostride = 1536; orowoff = 1024; cx = blk % 16; ry = blk / 16; }
  else if (blk < 3072) { blk -= 2304; in = Wout; out = WoT; C = 1536; ostride = 512;  orowoff = 0;    cx = blk % 48; ry = blk / 48; }
  else                 { blk -= 3072; in = Wrel; out = WrT; C = 512;  ostride = 192;  orowoff = 0;    cx = blk % 16; ry = blk / 16; }
  __shared__ float t[32][33];
  int tx = threadIdx.x & 31, ty = threadIdx.x >> 5;  // 32 x 8
  int r0 = ry * 32, c0 = cx * 32;
#pragma unroll
  for (int i = 0; i < 4; i++)
    t[ty + 8 * i][tx] = in[(size_t)(r0 + ty + 8 * i) * C + c0 + tx];
  __syncthreads();
#pragma unroll
  for (int i = 0; i < 4; i++)
    out[(size_t)(c0 + ty + 8 * i + orowoff) * ostride + r0 + tx] = (bf16)t[tx][ty + 8 * i];
}

// ---------- 8-wave GEMM core: 128(M)x64(N) tile, BK=64, XOR-swizzled LDS (R7-best) ----------
// 2-barrier gload_lds staging. 512 threads; wave w owns the 32x32 subtile at
// (wr,wc) = (w&3, w>>2). Per wave per K-step: 3 staging DMAs, 8 MFMAs; LDS 24 KB ->
// 3 blocks/CU x 8 waves = 24 waves/CU to hide the per-step vmcnt drain.
static __device__ __forceinline__ void gemm_core64(const bf16* __restrict__ A, const bf16* __restrict__ BT,
                                                   int Klen, int ldk, int m0, int n0, int M,
                                                   bf16* sa, bf16* sb, f32x4 acc[2][2]) {
  int tid = threadIdx.x, wave = tid >> 6, lane = tid & 63;
  int l15 = lane & 15, quad = lane >> 4;
  int lrow = lane >> 3, lcg = lane & 7;
  int wr = wave & 3, wc = wave >> 2;
  int swz = (lcg ^ lrow) * 8;  // row&7 == lrow for all staged rows

  // wave stages 16 A-rows (2 DMAs) and 8 B-rows (1 DMA)
  int rowA = wave * 16 + lrow;
  int ra0 = m0 + rowA;     if (ra0 > M - 1) ra0 = M - 1;
  int ra1 = m0 + rowA + 8; if (ra1 > M - 1) ra1 = M - 1;
  const bf16* pA0 = A + (size_t)ra0 * ldk + swz;
  const bf16* pA1 = A + (size_t)ra1 * ldk + swz;
  const bf16* pB = BT + (size_t)(n0 + wave * 8 + lrow) * ldk + swz;
  bf16* dA = sa + (wave * 16) * 64;
  bf16* dB = sb + (wave * 8) * 64;

  int swzA = (quad ^ (l15 & 7)) * 8;
  int swzB = ((4 + quad) ^ (l15 & 7)) * 8;
  const bf16* ar = sa + (wr * 32 + l15) * 64;
  const bf16* br = sb + (wc * 32 + l15) * 64;

  for (int k0 = 0; k0 < Klen; k0 += 64) {
    __syncthreads();
    gload_lds16(pA0 + k0, dA);
    gload_lds16(pA1 + k0, dA + 512);
    gload_lds16(pB + k0, dB);
    __syncthreads();
#pragma unroll
    for (int kq = 0; kq < 2; kq++) {
      int sz = kq ? swzB : swzA;
      bf16x8 af[2], bfr[2];
      af[0] = *(const bf16x8*)&ar[sz];
      af[1] = *(const bf16x8*)&ar[16 * 64 + sz];
      bfr[0] = *(const bf16x8*)&br[sz];
      bfr[1] = *(const bf16x8*)&br[16 * 64 + sz];
#pragma unroll
      for (int ct = 0; ct < 2; ct++)
#pragma unroll
        for (int rt = 0; rt < 2; rt++)
          acc[rt][ct] = mfma16(af[rt], bfr[ct], acc[rt][ct]);
    }
  }
}

// ---------- fused qkv + rel projection (128x64 tiles, 512 threads) ----------
// grid (24, 32); y 0-7 -> q cols (h = y), 8-15 -> k (h = y-8), 16-23 -> v (h = y-16,
// transposed to vt), 24-31 -> rel projection with repack epilogue.
__global__ __launch_bounds__(512, 4) void gemm_qkvrel(const bf16* __restrict__ xb, const bf16* __restrict__ WT,
                                                      const bf16* __restrict__ posb, const bf16* __restrict__ WrT,
                                                      const float* __restrict__ cb, const float* __restrict__ pb,
                                                      bf16* __restrict__ qc, bf16* __restrict__ qp,
                                                      bf16* __restrict__ kb, bf16* __restrict__ vt,
                                                      bf16* __restrict__ rk) {
  __shared__ __align__(16) bf16 smem[128 * 64 + 64 * 64];  // sa | sb ; tv (128*66) overlays
  bf16* sa = smem;
  bf16* sb = smem + 128 * 64;
  bf16* tv = smem;
  int tid = threadIdx.x, wave = tid >> 6, lane = tid & 63;
  int l15 = lane & 15, quad = lane >> 4;
  int wr = wave & 3, wc = wave >> 2;
  int m0 = blockIdx.x * 128;
  int y = blockIdx.y;
  f32x4 acc[2][2] = {};
  if (y >= 24) {
    // ---- rel projection path ----
    int n0 = (y - 24) * 64;
    gemm_core64(posb, WrT, 192, 192, m0, n0, NREL, sa, sb, acc);
#pragma unroll
    for (int rt = 0; rt < 2; rt++)
#pragma unroll
      for (int ct = 0; ct < 2; ct++)
#pragma unroll
        for (int r = 0; r < 4; r++) {
          int row = m0 + wr * 32 + rt * 16 + quad * 4 + r;
          if (row < NREL) {
            int col = n0 + wc * 32 + ct * 16 + l15;
            rk[((size_t)(col >> 6) * NRELP + row) * 64 + (col & 63)] = (bf16)acc[rt][ct][r];
          }
        }
    return;
  }
  gemm_core64(xb, WT, 1536, 1536, m0, y * 64, 3072, sa, sb, acc);
  int b = m0 / NSEQ, nseq0 = m0 % NSEQ;
  if (y < 16) {
    bool isq = y < 8;
    int h = y & 7;
#pragma unroll
    for (int rt = 0; rt < 2; rt++)
#pragma unroll
      for (int ct = 0; ct < 2; ct++)
#pragma unroll
        for (int r = 0; r < 4; r++) {
          int row = nseq0 + wr * 32 + rt * 16 + quad * 4 + r;
          int d = wc * 32 + ct * 16 + l15;       // within-head col
          int col = h * 64 + d;                  // within q|k 512-range (bias index)
          size_t o = ((size_t)(b * 8 + h) * NSEQ + row) * 64 + d;
          float v = acc[rt][ct][r];
          if (isq) {
            // 0.125 * log2(e): scores land directly in exp2 domain
            float qv = v * 0.18033688011f;
            qc[o] = (bf16)(qv + cb[col] * 1.44269504089f);
            qp[o] = (bf16)(qv + pb[col] * 1.44269504089f);
          } else {
            kb[o] = (bf16)v;
          }
        }
  } else {
    // v: transpose 128(n) x 64(dv) tile through LDS -> vt [bh][dv][n]; single head h = y-16
    int h = y - 16;
    __syncthreads();  // core's last reads done before tv overlay
#pragma unroll
    for (int rt = 0; rt < 2; rt++)
#pragma unroll
      for (int ct = 0; ct < 2; ct++)
#pragma unroll
        for (int r = 0; r < 4; r++)
          tv[(wr * 32 + rt * 16 + quad * 4 + r) * 66 + wc * 32 + ct * 16 + l15] = (bf16)acc[rt][ct][r];
    __syncthreads();
    int n = tid & 127, dq = tid >> 7;  // 128 x 4
#pragma unroll
    for (int i = 0; i < 16; i++) {
      int dv = i * 4 + dq;
      vt[((size_t)(b * 8 + h) * 64 + dv) * NSEQ + nseq0 + n] = tv[n * 66 + dv];
    }
  }
}

// ---------- output projection GEMM (+bias), fp32 out (128x64 tiles, 512 threads) ----------
__global__ __launch_bounds__(512, 4) void gemm_out(const bf16* __restrict__ A, const bf16* __restrict__ BT,
                                                   float* __restrict__ C, const float* __restrict__ bias) {
  __shared__ __align__(16) bf16 sa[128 * 64];
  __shared__ __align__(16) bf16 sb[64 * 64];
  int tid = threadIdx.x, wave = tid >> 6, lane = tid & 63;
  int l15 = lane & 15, quad = lane >> 4;
  int wr = wave & 3, wc = wave >> 2;
  int m0 = blockIdx.x * 128, n0 = blockIdx.y * 64;
  f32x4 acc[2][2] = {};
  gemm_core64(A, BT, 512, 512, m0, n0, 3072, sa, sb, acc);
#pragma unroll
  for (int rt = 0; rt < 2; rt++)
#pragma unroll
    for (int ct = 0; ct < 2; ct++)
#pragma unroll
      for (int r = 0; r < 4; r++) {
        int row = m0 + wr * 32 + rt * 16 + quad * 4 + r;
        int col = n0 + wc * 32 + ct * 16 + l15;
        C[(size_t)row * 1536 + col] = acc[rt][ct][r] + bias[col];
      }
}

// ---------- fused flash attention (converged best): reg-staged prefetch pipeline, kz=2 ----------
// grid (24 q-blocks of 64 rows, 16 bh, 2 kz); block 256 = 4 waves; wave w owns rows i0+16w..+16.
// Single-buffered LDS (40 KB); srel is a 2-slot ring of 64-row windows; K/V/rel staged via regs
// one tile ahead (loads fly under the full compute phase). V stays in LDS: V-from-global (R8/R9)
// is TA-bandwidth-worse (~64 B/cy vector-L1 path vs 128 B/cy DS broadcast) and spill-prone.
// Softmax: fixed shift 8, exp2 domain (q pre-scaled by log2e in the projection epilogue).
__global__ __launch_bounds__(256, 4) void attn(const bf16* __restrict__ qc, const bf16* __restrict__ qp,
                                               const bf16* __restrict__ kb, const bf16* __restrict__ vt,
                                               const bf16* __restrict__ rk,
                                               float* __restrict__ Opart, float* __restrict__ mlp) {
  __shared__ __align__(16) bf16 sk[64 * 64];     // rows = key, 8 slots of 16B, slot^=(row&7)
  __shared__ __align__(16) bf16 sv[64 * 64];     // rows = dv
  __shared__ __align__(16) bf16 srel[128 * 64];  // 2-slot ring of 64-row rel windows
  __shared__ __align__(16) bf16 pls[4][16 * 64]; // per-wave P transpose buffer, col ^= (row>>1)<<3
  int qb = blockIdx.x, bh = blockIdx.y, kz = blockIdx.z;
  int h = bh & 7;
  int i0 = qb * 64;
  int wave = threadIdx.x >> 6, lane = threadIdx.x & 63;
  int l15 = lane & 15, quad = lane >> 4;
  int lrow = lane >> 3, lcg = lane & 7;
  const bf16* qcb = qc + (size_t)bh * NSEQ * 64;
  const bf16* qpb = qp + (size_t)bh * NSEQ * 64;
  const bf16* kbb = kb + (size_t)bh * NSEQ * 64;
  const bf16* vtb = vt + (size_t)bh * 64 * NSEQ;
  const bf16* rkh = rk + (size_t)h * NRELP * 64;
  bf16* plsw = pls[wave];

  int qrow = i0 + wave * 16 + l15;
  bf16x8 aqc0 = *(const bf16x8*)(qcb + (size_t)qrow * 64 + quad * 8);
  bf16x8 aqc1 = *(const bf16x8*)(qcb + (size_t)qrow * 64 + 32 + quad * 8);
  bf16x8 aqp0 = *(const bf16x8*)(qpb + (size_t)qrow * 64 + quad * 8);
  bf16x8 aqp1 = *(const bf16x8*)(qpb + (size_t)qrow * 64 + 32 + quad * 8);

  // band-shift cross-lane setup: rl = quad*4+r
  int bidx[4];
  bool hisel[4];
#pragma unroll
  for (int r = 0; r < 4; r++) {
    int rl = quad * 4 + r;
    bidx[r] = (quad * 16 + ((l15 + 15 - rl) & 15)) << 2;
    hisel[r] = l15 > rl;
  }

  // ---- staging pointers: pre-swizzled global source, linear LDS dest ----
  int swz = (lcg ^ lrow) * 8;
  int jb = 23 + kz * 12 - qb;  // Rbase>>6 at jt=0; window jt reads 64-row windows jb+jt, jb+jt+1
  const bf16* pK = kbb + (size_t)(kz * 768 + wave * 16 + lrow) * 64 + swz;
  const bf16* pV = vtb + (size_t)(wave * 16 + lrow) * NSEQ + kz * 768 + swz;
  const bf16* pR = rkh + (size_t)(jb + 1) * 4096 + (size_t)(wave * 16 + lrow) * 64 + swz;
  bf16* wK = sk + (wave * 16 + lrow) * 64 + lcg * 8;   // linear col; source carries the XOR
  bf16* wV = sv + (wave * 16 + lrow) * 64 + lcg * 8;
  int wRoff = (wave * 16 + lrow) * 64 + lcg * 8;       // + ring-slot row offset at write time

  // prologue: low rel window [64*jb, 64*jb+64) into slot (jb&1) via DMA (drains at first barrier)
  {
    const bf16* pP = rkh + (size_t)jb * 4096 + (size_t)(wave * 16 + lrow) * 64 + swz;
    bf16* dP = srel + ((jb & 1) * 64 + wave * 16) * 64;
#pragma unroll
    for (int t = 0; t < 2; t++)
      gload_lds16(pP + t * 512, dP + t * 512);
  }
  // prologue: tile-0 K/V + high-window rel into staging regs
  float4 kr0 = *(const float4*)(pK), kr1 = *(const float4*)(pK + 512);             pK += 4096;
  float4 vr0 = *(const float4*)(pV), vr1 = *(const float4*)(pV + 8 * NSEQ);        pV += 64;
  float4 rr0 = *(const float4*)(pR), rr1 = *(const float4*)(pR + 512);             pR += 4096;
  int pxor = (jb & 1) << 6;  // logical loc -> physical row: phys = loc ^ pxor

  // read-side hoists (all row&7 terms reduce to l15&7)
  int swzA = (quad ^ (l15 & 7)) * 8;
  int swzB = ((4 + quad) ^ (l15 & 7)) * 8;
  int rb0 = (3 - wave) * 16 + l15;       // locbase + l15
  int pxl = (l15 >> 1) << 3;             // pls read xor
  const bf16* plr = plsw + l15 * 64;

  f32x4 acco[4] = {};
  float li[4] = {0.0f, 0.0f, 0.0f, 0.0f};

  for (int jt = 0; jt < 12; jt++) {
    __syncthreads();  // prior tile's LDS reads done; drains vmcnt for tile-jt staged regs
    *(float4*)(wK) = kr0;        *(float4*)(wK + 512) = kr1;
    *(float4*)(wV) = vr0;        *(float4*)(wV + 512) = vr1;
    {
      bf16* wR = srel + (pxor ^ 64) * 64 + wRoff;  // the slot NOT read last tile
      *(float4*)(wR) = rr0;      *(float4*)(wR + 512) = rr1;
    }
    __syncthreads();  // writes visible (no vmcnt ops in flight here)
    if (jt < 11) {    // issue tile-(jt+1) loads; they fly under this tile's compute
      kr0 = *(const float4*)(pK); kr1 = *(const float4*)(pK + 512);        pK += 4096;
      vr0 = *(const float4*)(pV); vr1 = *(const float4*)(pV + 8 * NSEQ);   pV += 64;
      rr0 = *(const float4*)(pR); rr1 = *(const float4*)(pR + 512);        pR += 4096;
    }
    // ---- content scores ----
    f32x4 s[4] = {};
#pragma unroll
    for (int c = 0; c < 4; c++) {
      const bf16* kp = sk + (c * 16 + l15) * 64;
      s[c] = mfma16(aqc0, *(const bf16x8*)(kp + swzA), s[c]);
      s[c] = mfma16(aqc1, *(const bf16x8*)(kp + swzB), s[c]);
    }
    // ---- banded rel scores (5 tiles of 16 from the ring window) ----
    f32x4 sb5[5];
#pragma unroll
    for (int cc = 0; cc < 5; cc++) {
      const bf16* rp = srel + ((rb0 + cc * 16) ^ pxor) * 64;
      f32x4 z = {};
      z = mfma16(aqp0, *(const bf16x8*)(rp + swzA), z);
      sb5[cc] = mfma16(aqp1, *(const bf16x8*)(rp + swzB), z);
    }
    // ---- shift-gather via bpermute ----
#pragma unroll
    for (int r = 0; r < 4; r++) {
      float bp[5];
#pragma unroll
      for (int cc = 0; cc < 5; cc++)
        bp[cc] = __int_as_float(__builtin_amdgcn_ds_bpermute(bidx[r], __float_as_int(sb5[cc][r])));
#pragma unroll
      for (int c = 0; c < 4; c++)
        s[c][r] += hisel[r] ? bp[c + 1] : bp[c];
    }
    // ---- fixed-shift exp2 + accumulate (8*log2e = 11.5415603) ----
#pragma unroll
    for (int c = 0; c < 4; c++)
#pragma unroll
      for (int r = 0; r < 4; r++) {
        float p = __builtin_amdgcn_exp2f(s[c][r] - 11.5415603f);
        bf16 pbh = (bf16)p;
        li[r] += (float)pbh;  // consistent with what PV consumes
        int prow = quad * 4 + r;
        plsw[prow * 64 + ((c * 16 + l15) ^ ((prow >> 1) << 3))] = pbh;
      }
    // ---- PV: A = P via pls, B = V from staged sv ----
#pragma unroll
    for (int ks = 0; ks < 2; ks++) {
      bf16x8 ap = *(const bf16x8*)(plr + ((ks * 32 + quad * 8) ^ pxl));
#pragma unroll
      for (int c = 0; c < 4; c++) {
        const bf16* vp = sv + (c * 16 + l15) * 64;
        acco[c] = mfma16(ap, *(const bf16x8*)(vp + (ks ? swzB : swzA)), acco[c]);
      }
    }
    pxor ^= 64;
  }
  // ---- final row sums + write unnormalized partials ----
#pragma unroll
  for (int r = 0; r < 4; r++)
    li[r] = rowsum16(li[r]);
  int qt16 = qb * 4 + wave;
  size_t pbase = ((size_t)(bh * 96 + qt16) * 2 + kz);
#pragma unroll
  for (int c = 0; c < 4; c++)
#pragma unroll
    for (int r = 0; r < 4; r++)
      Opart[pbase * 1024 + (quad * 4 + r) * 64 + c * 16 + l15] = acco[c][r];
  if (l15 == 0) {
#pragma unroll
    for (int r = 0; r < 4; r++)
      mlp[pbase * 16 + quad * 4 + r] = li[r];
  }
}

// ---------- merge the 2 key-split partials -> O bf16 [b][n][h][dv] ----------
__global__ void attn_merge(const float* __restrict__ Opart, const float* __restrict__ mlp,
                           bf16* __restrict__ O) {
  int qt = blockIdx.x, bh = blockIdx.y;
  int b = bh >> 3, h = bh & 7;
  int col = threadIdx.x & 63, rg = threadIdx.x >> 6;
  size_t base = (size_t)(bh * 96 + qt) * 2;
#pragma unroll
  for (int rr = 0; rr < 4; rr++) {
    int row = rg * 4 + rr;
    float L = mlp[base * 16 + row] + mlp[(base + 1) * 16 + row];
    float v = Opart[base * 1024 + row * 64 + col] + Opart[(base + 1) * 1024 + row * 64 + col];
    O[((size_t)(b * NSEQ + qt * 16 + row) * 8 + h) * 64 + col] = (bf16)(v / L);
  }
}

extern "C" void kernel_launch(void* const* d_in, const int* in_sizes, int n_in,
                              void* d_out, int out_size, void* d_ws, size_t ws_size,
                              hipStream_t stream) {
  const float* x    = (const float*)d_in[0];
  const float* Wq   = (const float*)d_in[1];
  const float* Wk   = (const float*)d_in[2];
  const float* Wv   = (const float*)d_in[3];
  const float* Wrel = (const float*)d_in[4];
  const float* Wout = (const float*)d_in[5];
  const float* bout = (const float*)d_in[6];
  const float* cb   = (const float*)d_in[7];
  const float* pb   = (const float*)d_in[8];
  const float* pos  = (const float*)d_in[9];
  float* out = (float*)d_out;

  char* ws = (char*)d_ws;
  size_t off = 0;
  auto alloc = [&](size_t bytes) {
    char* p = ws + off;
    off = (off + bytes + 255) & ~(size_t)255;
    return p;
  };
  bf16*  xb    = (bf16*)alloc(3072UL * 1536 * 2);
  bf16*  WT    = (bf16*)alloc(1536UL * 1536 * 2);   // [oc(q|k|v)][k]
  bf16*  WoT   = (bf16*)alloc(1536UL * 512 * 2);    // [outdim][k]
  bf16*  WrT   = (bf16*)alloc(512UL * 192 * 2);     // [oc][k]
  bf16*  posb  = (bf16*)alloc((size_t)NREL * 192 * 2);
  bf16*  qcb   = (bf16*)alloc(16UL * NSEQ * 64 * 2);
  bf16*  qpb   = (bf16*)alloc(16UL * NSEQ * 64 * 2);
  bf16*  kbb   = (bf16*)alloc(16UL * NSEQ * 64 * 2);
  bf16*  vtb   = (bf16*)alloc(16UL * NSEQ * 64 * 2);
  bf16*  rkb   = (bf16*)alloc(8UL * NRELP * 64 * 2);
  bf16*  Ob    = (bf16*)alloc(3072UL * 512 * 2);
  float* Opart = (float*)alloc(16UL * 96 * 2 * 1024 * 4);
  float* mlpw  = (float*)alloc(16UL * 96 * 2 * 16 * 4);

  // 1. all casts + weight transposes in one launch
  prep<<<dim3(8352), 256, 0, stream>>>(x, pos, Wq, Wk, Wv, Wout, Wrel, xb, posb, WT, WoT, WrT);
  // 2. qkv + rel projection, 128x64 8-wave tiles (R7-best)
  gemm_qkvrel<<<dim3(24, 32), 512, 0, stream>>>(xb, WT, posb, WrT, cb, pb, qcb, qpb, kbb, vtb, rkb);
  // 3. fused flash attention (converged best: reg-staged prefetch, V in LDS, kz=2)
  attn<<<dim3(24, 16, 2), 256, 0, stream>>>(qcb, qpb, kbb, vtb, rkb, Opart, mlpw);
  // 4. merge key-split partials
  attn_merge<<<dim3(96, 16), 256, 0, stream>>>(Opart, mlpw, Ob);
  // 5. output projection + bias, 128x64 8-wave tiles (R7-best)
  gemm_out<<<dim3(24, 24), 512, 0, stream>>>(Ob, WoT, out, bout);
}